// Round 2
// baseline (500.781 us; speedup 1.0000x reference)
//
#include <hip/hip_runtime.h>

// ---------------- problem constants ----------------
#define NN 100000      // nodes
#define NE 1600000     // edges (without self loops)
#define DD 128         // feature dim
#define EPSV 1e-5f

#define NSTRIP 6250            // NN/16 row-strips for MFMA gemms

// bucket sort: 196 buckets of 512 nodes; 782 hist/place blocks of 2048 edges
#define BSHIFT 9
#define NBUCK 196
#define EPB 2048
#define NHB 782

// sliced feature layout: 4 slices x 32 features; one slice-row = 16 uints = 64B
#define NSLICE 4
#define SLICE_U (NN * 16)      // uints per slice
#define AGG_RANGES 3125        // node ranges of 32 (3125*32 == NN)
#define AGG_CHUNKS 1563        // ceil(AGG_RANGES/2)

typedef __attribute__((ext_vector_type(8))) __bf16 bf16x8;
typedef __attribute__((ext_vector_type(4))) float f32x4;

union BF8 {                // bit-level construction of MFMA bf16 fragments
    ushort  us[8];
    uint    ui[4];
    uint4   u4;
    bf16x8  v;
};

__device__ __forceinline__ ushort f2bf(float f) {   // RNE fp32 -> bf16 bits
    uint u = __float_as_uint(f);
    return (ushort)((u + 0x7fffu + ((u >> 16) & 1u)) >> 16);
}
__device__ __forceinline__ float bflo(uint u) { return __uint_as_float(u << 16); }
__device__ __forceinline__ float bfhi(uint u) { return __uint_as_float(u & 0xffff0000u); }

// ---------------- bucketed counting sort (write-local CSR build) ----------------
__global__ __launch_bounds__(256)
void kb_hist(const int* __restrict__ col, int* __restrict__ bucket_cnt,
             int* __restrict__ blk_off) {
    __shared__ int h[256];
    int t = threadIdx.x;
    h[t] = 0;
    __syncthreads();
    int e0 = blockIdx.x * EPB;
    #pragma unroll
    for (int j = 0; j < 8; j++) {
        int e = e0 + t + j * 256;
        if (e < NE) atomicAdd(&h[col[e] >> BSHIFT], 1);
    }
    __syncthreads();
    int c = h[t];
    blk_off[blockIdx.x * 256 + t] = c ? atomicAdd(&bucket_cnt[t], c) : 0;
}

__global__ void kb_scan(const int* __restrict__ bucket_cnt, int* __restrict__ bucket_base) {
    __shared__ int s[256];
    int t = threadIdx.x;
    int v = bucket_cnt[t];
    s[t] = v;
    __syncthreads();
    for (int off = 1; off < 256; off <<= 1) {
        int u = (t >= off) ? s[t - off] : 0;
        __syncthreads();
        s[t] += u;
        __syncthreads();
    }
    bucket_base[t] = s[t] - v;
    if (t == 255) bucket_base[256] = s[255];
}

__global__ __launch_bounds__(256)
void kb_place(const int* __restrict__ row, const int* __restrict__ col,
              const int* __restrict__ bucket_base, const int* __restrict__ blk_off,
              uint* __restrict__ ebuf) {
    __shared__ int cur[256];
    int t = threadIdx.x;
    cur[t] = bucket_base[t] + blk_off[blockIdx.x * 256 + t];
    __syncthreads();
    int e0 = blockIdx.x * EPB;
    #pragma unroll
    for (int j = 0; j < 8; j++) {
        int e = e0 + t + j * 256;
        if (e < NE) {
            int c = col[e];
            int pos = atomicAdd(&cur[c >> BSHIFT], 1);
            ebuf[pos] = ((uint)row[e] << BSHIFT) | (uint)(c & ((1 << BSHIFT) - 1));
        }
    }
}

__global__ __launch_bounds__(256)
void kb_fin(const uint* __restrict__ ebuf, const int* __restrict__ bucket_base,
            int* __restrict__ row_ptr, float* __restrict__ dinv,
            int* __restrict__ csr) {
    __shared__ int deg[512];
    __shared__ int scn[256];
    int b = blockIdx.x;
    int n0 = b << BSHIFT;
    int t = threadIdx.x;
    deg[t] = 0; deg[t + 256] = 0;
    __syncthreads();
    int s = bucket_base[b], e = bucket_base[b + 1];
    for (int p = s + t; p < e; p += 256)
        atomicAdd(&deg[ebuf[p] & 511u], 1);
    __syncthreads();
    int d0 = deg[2 * t], d1 = deg[2 * t + 1];
    int pairsum = d0 + d1;
    scn[t] = pairsum;
    __syncthreads();
    for (int off = 1; off < 256; off <<= 1) {
        int u = (t >= off) ? scn[t - off] : 0;
        __syncthreads();
        scn[t] += u;
        __syncthreads();
    }
    int base = s + scn[t] - pairsum;
    int node0 = n0 + 2 * t;
    if (node0 < NN)     { row_ptr[node0]     = base;      dinv[node0]     = rsqrtf((float)(d0 + 1)); }
    if (node0 + 1 < NN) { row_ptr[node0 + 1] = base + d0; dinv[node0 + 1] = rsqrtf((float)(d1 + 1)); }
    __syncthreads();
    deg[2 * t] = base;
    deg[2 * t + 1] = base + d0;
    __syncthreads();
    for (int p = s + t; p < e; p += 256) {
        uint r = ebuf[p];
        int pos = atomicAdd(&deg[r & 511u], 1);
        csr[pos] = (int)(r >> BSHIFT);
    }
    if (b == 0 && t == 0) row_ptr[NN] = NE;
}

// ---------------- weight prep: 3x W[128x128] fp32 -> B-fragment order bf16 ----------------
__global__ void k_prepw3(const float* __restrict__ WA, const float* __restrict__ WB,
                         const float* __restrict__ WC, ushort* __restrict__ Wf) {
    int which = blockIdx.x >> 3;
    const float* W = (which == 0) ? WA : ((which == 1) ? WB : WC);
    int t = (blockIdx.x & 7) * 256 + threadIdx.x;
    int lane = t & 63;
    int kt = (t >> 6) & 3;
    int nt = t >> 8;
    int quad = lane >> 4;
    int n = nt * 16 + (lane & 15);
    BF8 f;
    #pragma unroll
    for (int j = 0; j < 8; j++)
        f.us[j] = f2bf(W[(kt * 32 + quad * 8 + j) * DD + n]);
    ((uint4*)(Wf + (size_t)which * 2048 * 8))[t] = f.u4;
}

// ---------------- GEMM1: G_bf16[sliced] = (bf16(X_f32) @ Wf) * dinv[row] ----------------
__global__ __launch_bounds__(256)
void k_gemmA(const float* __restrict__ X, const ushort* __restrict__ Wf,
             const float* __restrict__ dinv, ushort* __restrict__ Y) {
    int strip = blockIdx.x * 4 + (threadIdx.x >> 6);
    if (strip >= NSTRIP) return;
    int lane = threadIdx.x & 63;
    int quad = lane >> 4;
    int m = lane & 15;
    int row = strip * 16 + m;

    BF8 a[4];
    #pragma unroll
    for (int kt = 0; kt < 4; kt++) {
        const float* xp = X + (size_t)row * DD + kt * 32 + quad * 8;
        float4 v0 = *(const float4*)xp;
        float4 v1 = *(const float4*)(xp + 4);
        a[kt].us[0] = f2bf(v0.x); a[kt].us[1] = f2bf(v0.y);
        a[kt].us[2] = f2bf(v0.z); a[kt].us[3] = f2bf(v0.w);
        a[kt].us[4] = f2bf(v1.x); a[kt].us[5] = f2bf(v1.y);
        a[kt].us[6] = f2bf(v1.z); a[kt].us[7] = f2bf(v1.w);
    }

    float4 dv = *(const float4*)(dinv + strip * 16 + quad * 4);
    float dvr[4] = {dv.x, dv.y, dv.z, dv.w};

    #pragma unroll
    for (int nt = 0; nt < 8; nt++) {
        f32x4 acc = {0.f, 0.f, 0.f, 0.f};
        #pragma unroll
        for (int kt = 0; kt < 4; kt++) {
            BF8 b;
            b.u4 = ((const uint4*)Wf)[(nt * 4 + kt) * 64 + lane];
            acc = __builtin_amdgcn_mfma_f32_16x16x32_bf16(a[kt].v, b.v, acc, 0, 0, 0);
        }
        // sliced write: slice = nt>>1, within-slice ushort idx = (nt&1)*16 + m
        ushort* yb = Y + (nt >> 1) * (2 * SLICE_U) + (nt & 1) * 16 + m;
        #pragma unroll
        for (int r = 0; r < 4; r++)
            yb[(strip * 16 + quad * 4 + r) * 32] = f2bf(acc[r] * dvr[r]);
    }
}

// ---------------- GEMM2: G = (bf16(relu(norm(X_sliced))) @ Wf) * dinv[row] ----------------
__global__ __launch_bounds__(256)
void k_gemmB(const uint* __restrict__ Xp, const ushort* __restrict__ Wf,
             const float* __restrict__ mul, const float* __restrict__ add,
             const float* __restrict__ dinv, ushort* __restrict__ Y) {
    int strip = blockIdx.x * 4 + (threadIdx.x >> 6);
    if (strip >= NSTRIP) return;
    int lane = threadIdx.x & 63;
    int quad = lane >> 4;
    int m = lane & 15;
    int row = strip * 16 + m;

    BF8 a[4];
    #pragma unroll
    for (int kt = 0; kt < 4; kt++) {
        int f = kt * 32 + quad * 8;
        // sliced read: slice = kt, uint offset within slice-row = quad*4
        uint4 xu = *(const uint4*)(Xp + kt * SLICE_U + row * 16 + quad * 4);
        float4 m0 = *(const float4*)(mul + f);
        float4 m1 = *(const float4*)(mul + f + 4);
        float4 a0 = *(const float4*)(add + f);
        float4 a1 = *(const float4*)(add + f + 4);
        uint xs[4] = {xu.x, xu.y, xu.z, xu.w};
        float mm[8] = {m0.x, m0.y, m0.z, m0.w, m1.x, m1.y, m1.z, m1.w};
        float aa[8] = {a0.x, a0.y, a0.z, a0.w, a1.x, a1.y, a1.z, a1.w};
        #pragma unroll
        for (int p = 0; p < 4; p++) {
            float lo = bflo(xs[p]), hi = bfhi(xs[p]);
            a[kt].us[2 * p]     = f2bf(fmaxf(0.f, fmaf(lo, mm[2 * p],     aa[2 * p])));
            a[kt].us[2 * p + 1] = f2bf(fmaxf(0.f, fmaf(hi, mm[2 * p + 1], aa[2 * p + 1])));
        }
    }

    float4 dv = *(const float4*)(dinv + strip * 16 + quad * 4);
    float dvr[4] = {dv.x, dv.y, dv.z, dv.w};

    #pragma unroll
    for (int nt = 0; nt < 8; nt++) {
        f32x4 acc = {0.f, 0.f, 0.f, 0.f};
        #pragma unroll
        for (int kt = 0; kt < 4; kt++) {
            BF8 b;
            b.u4 = ((const uint4*)Wf)[(nt * 4 + kt) * 64 + lane];
            acc = __builtin_amdgcn_mfma_f32_16x16x32_bf16(a[kt].v, b.v, acc, 0, 0, 0);
        }
        ushort* yb = Y + (nt >> 1) * (2 * SLICE_U) + (nt & 1) * 16 + m;
        #pragma unroll
        for (int r = 0; r < 4; r++)
            yb[(strip * 16 + quad * 4 + r) * 32] = f2bf(acc[r] * dvr[r]);
    }
}

// ---------------- sliced aggregation + fused GraphNorm stats ----------------
// 4 feature slices (32 feats / 64B rows). Grid = chunk*8 + r8; r8 -> XCD via
// round-robin dispatch, slice = r8&3  =>  slice s lives on XCDs {s, s+4} only:
// per-XCD gather working set 6.4 MB (vs 25.6 MB unsliced) against 4 MB L2.
// Wave = 1 node-slice: 16 lanes per neighbor (64B), 4 neighbors per gather.
// NOTE: lanes are 4-way redundant over features (j = lane>>4 is the neighbor
// sub-index), so the self-loop term must be added exactly ONCE, after the
// cross-group shfl reduce — adding it into each j-group counts it 4x (R1 bug).
__global__ __launch_bounds__(256)
void k_aggs(const uint* __restrict__ Hs, const int* __restrict__ row_ptr,
            const int* __restrict__ csr, const float* __restrict__ dinv,
            const float* __restrict__ bias, uint* __restrict__ Ys,
            float* __restrict__ psumG, float* __restrict__ psqG) {
    const int lane = threadIdx.x & 63;
    const int wid  = threadIdx.x >> 6;
    const int r8   = blockIdx.x & 7;
    const int chunk = blockIdx.x >> 3;
    const int slice = r8 & 3;
    const int range = chunk * 2 + (r8 >> 2);
    if (range >= AGG_RANGES) return;       // uniform per block
    const int j = lane >> 4;               // neighbor sub-index 0..3
    const int u = lane & 15;               // uint index within 64B slice row
    const uint* __restrict__ H = Hs + slice * SLICE_U;
    uint* __restrict__ Yp = Ys + slice * SLICE_U;
    const float2 bb = *(const float2*)(bias + slice * 32 + 2 * u);

    float ss0 = 0.f, ss1 = 0.f, sq0 = 0.f, sq1 = 0.f;
    const int n0 = range * 32 + wid * 8;
    for (int t = 0; t < 8; t++) {
        const int i = __builtin_amdgcn_readfirstlane(n0 + t);
        const int p0 = row_ptr[i], p1 = row_ptr[i + 1];
        uint hs = H[(uint)i * 16u + u];
        const float sl0 = bflo(hs), sl1 = bfhi(hs);   // self-loop term (once!)
        float a0 = 0.f, a1 = 0.f;
        float b0 = 0.f, b1 = 0.f, c0 = 0.f, c1 = 0.f, d0 = 0.f, d1 = 0.f;
        int p = p0;
        for (; p + 16 <= p1; p += 16) {
            int s0 = csr[p + j];
            int s1 = csr[p + 4 + j];
            int s2 = csr[p + 8 + j];
            int s3 = csr[p + 12 + j];
            uint h0 = H[(uint)s0 * 16u + u];
            uint h1 = H[(uint)s1 * 16u + u];
            uint h2 = H[(uint)s2 * 16u + u];
            uint h3 = H[(uint)s3 * 16u + u];
            a0 += bflo(h0); a1 += bfhi(h0);
            b0 += bflo(h1); b1 += bfhi(h1);
            c0 += bflo(h2); c1 += bfhi(h2);
            d0 += bflo(h3); d1 += bfhi(h3);
        }
        for (; p < p1; p += 4) {                      // predicated 4-wide tail
            int q = p + j;
            int sx = csr[q < p1 ? q : p1 - 1];
            uint h0 = H[(uint)sx * 16u + u];
            if (q >= p1) h0 = 0u;
            a0 += bflo(h0); a1 += bfhi(h0);
        }
        float e0 = (a0 + b0) + (c0 + d0);
        float e1 = (a1 + b1) + (c1 + d1);
        e0 += __shfl_xor(e0, 16, 64);
        e1 += __shfl_xor(e1, 16, 64);
        e0 += __shfl_xor(e0, 32, 64);
        e1 += __shfl_xor(e1, 32, 64);
        e0 += sl0;                                    // self added exactly once
        e1 += sl1;
        const float di = dinv[i];
        float r0 = fmaf(e0, di, bb.x);
        float r1 = fmaf(e1, di, bb.y);
        if (lane < 16)
            Yp[(uint)i * 16u + u] = (uint)f2bf(r0) | ((uint)f2bf(r1) << 16);
        ss0 += r0; sq0 = fmaf(r0, r0, sq0);           // fused GraphNorm stats
        ss1 += r1; sq1 = fmaf(r1, r1, sq1);
    }
    __shared__ float ls[4][32], lq[4][32];
    if (lane < 16) {
        ls[wid][2 * u] = ss0; ls[wid][2 * u + 1] = ss1;
        lq[wid][2 * u] = sq0; lq[wid][2 * u + 1] = sq1;
    }
    __syncthreads();
    if (threadIdx.x < 32) {
        int f = threadIdx.x;
        atomicAdd(&psumG[slice * 32 + f], ls[0][f] + ls[1][f] + ls[2][f] + ls[3][f]);
        atomicAdd(&psqG [slice * 32 + f], lq[0][f] + lq[1][f] + lq[2][f] + lq[3][f]);
    }
}

// ---------------- GraphNorm params from fused global accumulators ----------------
__global__ void k_nparams(const float* __restrict__ psum, const float* __restrict__ psq,
                          const float* __restrict__ w, const float* __restrict__ b,
                          const float* __restrict__ a,
                          float* __restrict__ mul, float* __restrict__ add) {
    int f = threadIdx.x;
    const float invn = 1.0f / (float)NN;
    float m = psum[f] * invn;
    float ex2 = psq[f] * invn;
    float av = a[f];
    float var = ex2 - m * m * (2.f * av - av * av);
    float inv = rsqrtf(var + EPSV);
    mul[f] = w[f] * inv;
    add[f] = b[f] - w[f] * inv * av * m;
}

// ---------------- fused MLP head (MFMA): out = relu(T(X)@W + b0h) @ v1 + b1 ----------------
__global__ __launch_bounds__(256)
void k_mlp(const uint* __restrict__ Xp, const ushort* __restrict__ Wf,
           const float* __restrict__ mul, const float* __restrict__ add,
           const float* __restrict__ b0h, const float* __restrict__ v1,
           const float* __restrict__ b1, float* __restrict__ out) {
    int strip = blockIdx.x * 4 + (threadIdx.x >> 6);
    if (strip >= NSTRIP) return;
    int lane = threadIdx.x & 63;
    int quad = lane >> 4;
    int m = lane & 15;
    int row = strip * 16 + m;

    BF8 a[4];
    #pragma unroll
    for (int kt = 0; kt < 4; kt++) {
        int f = kt * 32 + quad * 8;
        uint4 xu = *(const uint4*)(Xp + kt * SLICE_U + row * 16 + quad * 4);
        float4 m0 = *(const float4*)(mul + f);
        float4 m1 = *(const float4*)(mul + f + 4);
        float4 a0 = *(const float4*)(add + f);
        float4 a1 = *(const float4*)(add + f + 4);
        uint xs[4] = {xu.x, xu.y, xu.z, xu.w};
        float mm[8] = {m0.x, m0.y, m0.z, m0.w, m1.x, m1.y, m1.z, m1.w};
        float aa[8] = {a0.x, a0.y, a0.z, a0.w, a1.x, a1.y, a1.z, a1.w};
        #pragma unroll
        for (int p = 0; p < 4; p++) {
            float lo = bflo(xs[p]), hi = bfhi(xs[p]);
            a[kt].us[2 * p]     = f2bf(fmaxf(0.f, fmaf(lo, mm[2 * p],     aa[2 * p])));
            a[kt].us[2 * p + 1] = f2bf(fmaxf(0.f, fmaf(hi, mm[2 * p + 1], aa[2 * p + 1])));
        }
    }

    float part[4] = {0.f, 0.f, 0.f, 0.f};
    #pragma unroll
    for (int nt = 0; nt < 8; nt++) {
        f32x4 acc = {0.f, 0.f, 0.f, 0.f};
        #pragma unroll
        for (int kt = 0; kt < 4; kt++) {
            BF8 b;
            b.u4 = ((const uint4*)Wf)[(nt * 4 + kt) * 64 + lane];
            acc = __builtin_amdgcn_mfma_f32_16x16x32_bf16(a[kt].v, b.v, acc, 0, 0, 0);
        }
        int colg = nt * 16 + m;
        float bb = b0h[colg];
        float vv = v1[colg];
        #pragma unroll
        for (int r = 0; r < 4; r++)
            part[r] = fmaf(fmaxf(0.f, acc[r] + bb), vv, part[r]);
    }
    #pragma unroll
    for (int r = 0; r < 4; r++) {
        #pragma unroll
        for (int off = 1; off < 16; off <<= 1)
            part[r] += __shfl_xor(part[r], off, 64);
    }
    if (m == 0) {
        float ob = b1[0];
        #pragma unroll
        for (int r = 0; r < 4; r++)
            out[strip * 16 + quad * 4 + r] = part[r] + ob;
    }
}

// ---------------- launch ----------------
static inline char* wsalloc(char*& p, size_t bytes) {
    char* r = p;
    p += (bytes + 255) & ~(size_t)255;
    return r;
}

extern "C" void kernel_launch(void* const* d_in, const int* in_sizes, int n_in,
                              void* d_out, int out_size, void* d_ws, size_t ws_size,
                              hipStream_t stream) {
    const float* x     = (const float*)d_in[0];
    const int*   ei    = (const int*)d_in[1];
    const int*   row   = ei;
    const int*   col   = ei + NE;
    const float* W0    = (const float*)d_in[2];
    const float* b0    = (const float*)d_in[3];
    const float* W1    = (const float*)d_in[4];
    const float* b1    = (const float*)d_in[5];
    const float* gn0w  = (const float*)d_in[6];
    const float* gn0b  = (const float*)d_in[7];
    const float* gn0a  = (const float*)d_in[8];
    const float* gn1w  = (const float*)d_in[9];
    const float* gn1b  = (const float*)d_in[10];
    const float* gn1a  = (const float*)d_in[11];
    const float* lin0w = (const float*)d_in[12];
    const float* lin0b = (const float*)d_in[13];
    const float* lin1w = (const float*)d_in[14];
    const float* lin1b = (const float*)d_in[15];
    float* out = (float*)d_out;

    char* p = (char*)d_ws;
    ushort* bufA   = (ushort*)wsalloc(p, (size_t)NN * DD * 2);   // bf16 sliced g
    ushort* bufB   = (ushort*)wsalloc(p, (size_t)NN * DD * 2);   // bf16 sliced agg out
    int*    csr    = (int*)   wsalloc(p, (size_t)NE * 4);
    uint*   ebuf   = (uint*)  wsalloc(p, (size_t)NE * 4);
    int*    blk_off= (int*)   wsalloc(p, (size_t)NHB * 256 * 4);
    int*    bucket_cnt = (int*)wsalloc(p, 256 * 4);
    int*    bucket_base= (int*)wsalloc(p, 257 * 4);
    int*    row_ptr= (int*)   wsalloc(p, (size_t)(NN + 1) * 4);
    float*  dinv   = (float*) wsalloc(p, (size_t)NN * 4);
    float*  statsG = (float*) wsalloc(p, 512 * 4);   // [sum0|sq0|sum1|sq1] x 128
    float*  mulv   = (float*) wsalloc(p, DD * 4);
    float*  addv   = (float*) wsalloc(p, DD * 4);
    ushort* Wf     = (ushort*)wsalloc(p, 3 * 2048 * 8 * 2);

    hipMemsetAsync(bucket_cnt, 0, 256 * 4, stream);
    hipMemsetAsync(statsG, 0, 512 * 4, stream);

    // graph build: bucketed counting sort; degrees/row_ptr/dinv derived bucket-locally
    kb_hist <<<NHB, 256, 0, stream>>>(col, bucket_cnt, blk_off);
    kb_scan <<<1, 256, 0, stream>>>(bucket_cnt, bucket_base);
    kb_place<<<NHB, 256, 0, stream>>>(row, col, bucket_base, blk_off, ebuf);
    kb_fin  <<<NBUCK, 256, 0, stream>>>(ebuf, bucket_base, row_ptr, dinv, csr);

    // weight prep
    k_prepw3<<<24, 256, 0, stream>>>(W0, W1, lin0w, Wf);
    ushort* Wf0 = Wf;
    ushort* Wf1 = Wf + 2048 * 8;
    ushort* Wf2 = Wf + 2 * 2048 * 8;

    const int GB = (NSTRIP + 3) / 4;
    const int AGB = AGG_CHUNKS * 8;

    // stage 1
    k_gemmA<<<GB, 256, 0, stream>>>(x, Wf0, dinv, bufA);
    k_aggs <<<AGB, 256, 0, stream>>>((const uint*)bufA, row_ptr, csr, dinv, b0,
                                     (uint*)bufB, statsG, statsG + 128);
    k_nparams<<<1, 128, 0, stream>>>(statsG, statsG + 128, gn0w, gn0b, gn0a, mulv, addv);

    // stage 2
    k_gemmB<<<GB, 256, 0, stream>>>((const uint*)bufB, Wf1, mulv, addv, dinv, bufA);
    k_aggs <<<AGB, 256, 0, stream>>>((const uint*)bufA, row_ptr, csr, dinv, b1,
                                     (uint*)bufB, statsG + 256, statsG + 384);
    k_nparams<<<1, 128, 0, stream>>>(statsG + 256, statsG + 384, gn1w, gn1b, gn1a, mulv, addv);

    // fused MLP head
    k_mlp<<<GB, 256, 0, stream>>>((const uint*)bufB, Wf2, mulv, addv,
                                  lin0b, lin1w, lin1b, out);

    (void)in_sizes; (void)n_in; (void)out_size; (void)ws_size;
}

// Round 3
// 416.471 us; speedup vs baseline: 1.2024x; 1.2024x over previous
//
#include <hip/hip_runtime.h>

// ---------------- problem constants ----------------
#define NN 100000      // nodes
#define NE 1600000     // edges (without self loops)
#define DD 128         // feature dim
#define EPSV 1e-5f

#define NSTRIP 6250            // NN/16 row-strips for MFMA gemms

// bucket sort: 196 buckets of 512 nodes; 782 hist/place blocks of 2048 edges
#define BSHIFT 9
#define NBUCK 196
#define EPB 2048
#define NHB 782

typedef __attribute__((ext_vector_type(8))) __bf16 bf16x8;
typedef __attribute__((ext_vector_type(4))) float f32x4;

union BF8 {                // bit-level construction of MFMA bf16 fragments
    ushort  us[8];
    uint    ui[4];
    uint4   u4;
    bf16x8  v;
};

__device__ __forceinline__ ushort f2bf(float f) {   // RNE fp32 -> bf16 bits
    uint u = __float_as_uint(f);
    return (ushort)((u + 0x7fffu + ((u >> 16) & 1u)) >> 16);
}
__device__ __forceinline__ float bflo(uint u) { return __uint_as_float(u << 16); }
__device__ __forceinline__ float bfhi(uint u) { return __uint_as_float(u & 0xffff0000u); }

// ---------------- bucketed counting sort (write-local CSR build) ----------------
__global__ __launch_bounds__(256)
void kb_hist(const int* __restrict__ col, int* __restrict__ bucket_cnt,
             int* __restrict__ blk_off) {
    __shared__ int h[256];
    int t = threadIdx.x;
    h[t] = 0;
    __syncthreads();
    int e0 = blockIdx.x * EPB;
    #pragma unroll
    for (int j = 0; j < 8; j++) {
        int e = e0 + t + j * 256;
        if (e < NE) atomicAdd(&h[col[e] >> BSHIFT], 1);
    }
    __syncthreads();
    int c = h[t];
    blk_off[blockIdx.x * 256 + t] = c ? atomicAdd(&bucket_cnt[t], c) : 0;
}

__global__ void kb_scan(const int* __restrict__ bucket_cnt, int* __restrict__ bucket_base) {
    __shared__ int s[256];
    int t = threadIdx.x;
    int v = bucket_cnt[t];
    s[t] = v;
    __syncthreads();
    for (int off = 1; off < 256; off <<= 1) {
        int u = (t >= off) ? s[t - off] : 0;
        __syncthreads();
        s[t] += u;
        __syncthreads();
    }
    bucket_base[t] = s[t] - v;
    if (t == 255) bucket_base[256] = s[255];
}

__global__ __launch_bounds__(256)
void kb_place(const int* __restrict__ row, const int* __restrict__ col,
              const int* __restrict__ bucket_base, const int* __restrict__ blk_off,
              uint* __restrict__ ebuf) {
    __shared__ int cur[256];
    int t = threadIdx.x;
    cur[t] = bucket_base[t] + blk_off[blockIdx.x * 256 + t];
    __syncthreads();
    int e0 = blockIdx.x * EPB;
    #pragma unroll
    for (int j = 0; j < 8; j++) {
        int e = e0 + t + j * 256;
        if (e < NE) {
            int c = col[e];
            int pos = atomicAdd(&cur[c >> BSHIFT], 1);
            ebuf[pos] = ((uint)row[e] << BSHIFT) | (uint)(c & ((1 << BSHIFT) - 1));
        }
    }
}

__global__ __launch_bounds__(256)
void kb_fin(const uint* __restrict__ ebuf, const int* __restrict__ bucket_base,
            int* __restrict__ row_ptr, float* __restrict__ dinv,
            int* __restrict__ csr) {
    __shared__ int deg[512];
    __shared__ int scn[256];
    int b = blockIdx.x;
    int n0 = b << BSHIFT;
    int t = threadIdx.x;
    deg[t] = 0; deg[t + 256] = 0;
    __syncthreads();
    int s = bucket_base[b], e = bucket_base[b + 1];
    for (int p = s + t; p < e; p += 256)
        atomicAdd(&deg[ebuf[p] & 511u], 1);
    __syncthreads();
    int d0 = deg[2 * t], d1 = deg[2 * t + 1];
    int pairsum = d0 + d1;
    scn[t] = pairsum;
    __syncthreads();
    for (int off = 1; off < 256; off <<= 1) {
        int u = (t >= off) ? scn[t - off] : 0;
        __syncthreads();
        scn[t] += u;
        __syncthreads();
    }
    int base = s + scn[t] - pairsum;          // global CSR offset of node n0+2t
    int node0 = n0 + 2 * t;
    if (node0 < NN)     { row_ptr[node0]     = base;      dinv[node0]     = rsqrtf((float)(d0 + 1)); }
    if (node0 + 1 < NN) { row_ptr[node0 + 1] = base + d0; dinv[node0 + 1] = rsqrtf((float)(d1 + 1)); }
    __syncthreads();                           // before reusing deg[] as cursors
    deg[2 * t] = base;
    deg[2 * t + 1] = base + d0;
    __syncthreads();
    for (int p = s + t; p < e; p += 256) {
        uint r = ebuf[p];
        int pos = atomicAdd(&deg[r & 511u], 1);
        csr[pos] = (int)(r >> BSHIFT);         // 4B record: src only
    }
    if (b == 0 && t == 0) row_ptr[NN] = NE;
}

// ---------------- weight prep: 3x W[128x128] fp32 -> B-fragment order bf16 ----------------
__global__ void k_prepw3(const float* __restrict__ WA, const float* __restrict__ WB,
                         const float* __restrict__ WC, ushort* __restrict__ Wf) {
    int which = blockIdx.x >> 3;
    const float* W = (which == 0) ? WA : ((which == 1) ? WB : WC);
    int t = (blockIdx.x & 7) * 256 + threadIdx.x;    // 0..2047
    int lane = t & 63;
    int kt = (t >> 6) & 3;
    int nt = t >> 8;
    int quad = lane >> 4;
    int n = nt * 16 + (lane & 15);
    BF8 f;
    #pragma unroll
    for (int j = 0; j < 8; j++)
        f.us[j] = f2bf(W[(kt * 32 + quad * 8 + j) * DD + n]);
    ((uint4*)(Wf + (size_t)which * 2048 * 8))[t] = f.u4;
}

// ---------------- GEMM1: G_bf16[N,128] = (bf16(X_f32) @ Wf) * dinv[row] ----------------
__global__ __launch_bounds__(256)
void k_gemmA(const float* __restrict__ X, const ushort* __restrict__ Wf,
             const float* __restrict__ dinv, ushort* __restrict__ Y) {
    int strip = blockIdx.x * 4 + (threadIdx.x >> 6);
    if (strip >= NSTRIP) return;
    int lane = threadIdx.x & 63;
    int quad = lane >> 4;
    int m = lane & 15;
    int row = strip * 16 + m;

    BF8 a[4];
    #pragma unroll
    for (int kt = 0; kt < 4; kt++) {
        const float* xp = X + (size_t)row * DD + kt * 32 + quad * 8;
        float4 v0 = *(const float4*)xp;
        float4 v1 = *(const float4*)(xp + 4);
        a[kt].us[0] = f2bf(v0.x); a[kt].us[1] = f2bf(v0.y);
        a[kt].us[2] = f2bf(v0.z); a[kt].us[3] = f2bf(v0.w);
        a[kt].us[4] = f2bf(v1.x); a[kt].us[5] = f2bf(v1.y);
        a[kt].us[6] = f2bf(v1.z); a[kt].us[7] = f2bf(v1.w);
    }

    float4 dv = *(const float4*)(dinv + strip * 16 + quad * 4);
    float dvr[4] = {dv.x, dv.y, dv.z, dv.w};

    #pragma unroll
    for (int nt = 0; nt < 8; nt++) {
        f32x4 acc = {0.f, 0.f, 0.f, 0.f};
        #pragma unroll
        for (int kt = 0; kt < 4; kt++) {
            BF8 b;
            b.u4 = ((const uint4*)Wf)[(nt * 4 + kt) * 64 + lane];
            acc = __builtin_amdgcn_mfma_f32_16x16x32_bf16(a[kt].v, b.v, acc, 0, 0, 0);
        }
        int colg = nt * 16 + m;
        #pragma unroll
        for (int r = 0; r < 4; r++)
            Y[(size_t)(strip * 16 + quad * 4 + r) * DD + colg] = f2bf(acc[r] * dvr[r]);
    }
}

// ---------------- GEMM2: G = (bf16(relu(norm(X_bf16))) @ Wf) * dinv[row] ----------------
__global__ __launch_bounds__(256)
void k_gemmB(const uint* __restrict__ Xp, const ushort* __restrict__ Wf,
             const float* __restrict__ mul, const float* __restrict__ add,
             const float* __restrict__ dinv, ushort* __restrict__ Y) {
    int strip = blockIdx.x * 4 + (threadIdx.x >> 6);
    if (strip >= NSTRIP) return;
    int lane = threadIdx.x & 63;
    int quad = lane >> 4;
    int m = lane & 15;
    int row = strip * 16 + m;

    BF8 a[4];
    #pragma unroll
    for (int kt = 0; kt < 4; kt++) {
        int f = kt * 32 + quad * 8;
        uint4 xu = *(const uint4*)(Xp + (size_t)row * 64 + kt * 16 + quad * 4);
        float4 m0 = *(const float4*)(mul + f);
        float4 m1 = *(const float4*)(mul + f + 4);
        float4 a0 = *(const float4*)(add + f);
        float4 a1 = *(const float4*)(add + f + 4);
        uint xs[4] = {xu.x, xu.y, xu.z, xu.w};
        float mm[8] = {m0.x, m0.y, m0.z, m0.w, m1.x, m1.y, m1.z, m1.w};
        float aa[8] = {a0.x, a0.y, a0.z, a0.w, a1.x, a1.y, a1.z, a1.w};
        #pragma unroll
        for (int p = 0; p < 4; p++) {
            float lo = bflo(xs[p]), hi = bfhi(xs[p]);
            a[kt].us[2 * p]     = f2bf(fmaxf(0.f, fmaf(lo, mm[2 * p],     aa[2 * p])));
            a[kt].us[2 * p + 1] = f2bf(fmaxf(0.f, fmaf(hi, mm[2 * p + 1], aa[2 * p + 1])));
        }
    }

    float4 dv = *(const float4*)(dinv + strip * 16 + quad * 4);
    float dvr[4] = {dv.x, dv.y, dv.z, dv.w};

    #pragma unroll
    for (int nt = 0; nt < 8; nt++) {
        f32x4 acc = {0.f, 0.f, 0.f, 0.f};
        #pragma unroll
        for (int kt = 0; kt < 4; kt++) {
            BF8 b;
            b.u4 = ((const uint4*)Wf)[(nt * 4 + kt) * 64 + lane];
            acc = __builtin_amdgcn_mfma_f32_16x16x32_bf16(a[kt].v, b.v, acc, 0, 0, 0);
        }
        int colg = nt * 16 + m;
        #pragma unroll
        for (int r = 0; r < 4; r++)
            Y[(size_t)(strip * 16 + quad * 4 + r) * DD + colg] = f2bf(acc[r] * dvr[r]);
    }
}

// ---------------- aggregation: Y[i] = di*( sum_e g[src_e] + g[i] ) + bias ----------------
// 256 threads = 4 waves = 4 nodes; 8 gathers in flight per wave.
// GraphNorm stats fused into the epilogue: per-block LDS reduce over the 4
// nodes, then 8-way-sharded (blockIdx&7) global atomicAdd per feature:
// 25000 blocks / 8 shards = 3125 serialized adds per address, parallel over
// 1024 distinct addresses -> negligible vs 60us kernel.
__global__ __launch_bounds__(256)
void k_agg2(const uint* __restrict__ H2,
            const int* __restrict__ row_ptr, const int* __restrict__ csr,
            const float* __restrict__ dinv,
            const float* __restrict__ bias, uint* __restrict__ Y2,
            float* __restrict__ psumG, float* __restrict__ psqG) {
    const int lane = threadIdx.x & 63;
    const int wid  = threadIdx.x >> 6;
    // node index is wave-uniform: force into SGPR so row_ptr/csr loads scalarize
    const int i = __builtin_amdgcn_readfirstlane(blockIdx.x * 4 + wid);
    const int p0 = row_ptr[i], p1 = row_ptr[i + 1];
    const float di = dinv[i];
    uint su = H2[(size_t)i * 64 + lane];
    float a0 = bflo(su), a1 = bfhi(su);            // self loop term g[i]
    float b0 = 0.f, b1 = 0.f, c0 = 0.f, c1 = 0.f, d0 = 0.f, d1 = 0.f;
    int p = p0;
    for (; p + 7 < p1; p += 8) {                   // 8 loads in flight
        int s0 = csr[p],     s1 = csr[p + 1], s2 = csr[p + 2], s3 = csr[p + 3];
        int s4 = csr[p + 4], s5 = csr[p + 5], s6 = csr[p + 6], s7 = csr[p + 7];
        uint h0 = H2[(size_t)s0 * 64 + lane];
        uint h1 = H2[(size_t)s1 * 64 + lane];
        uint h2 = H2[(size_t)s2 * 64 + lane];
        uint h3 = H2[(size_t)s3 * 64 + lane];
        uint h4 = H2[(size_t)s4 * 64 + lane];
        uint h5 = H2[(size_t)s5 * 64 + lane];
        uint h6 = H2[(size_t)s6 * 64 + lane];
        uint h7 = H2[(size_t)s7 * 64 + lane];
        a0 += bflo(h0); a1 += bfhi(h0);
        b0 += bflo(h1); b1 += bfhi(h1);
        c0 += bflo(h2); c1 += bfhi(h2);
        d0 += bflo(h3); d1 += bfhi(h3);
        a0 += bflo(h4); a1 += bfhi(h4);
        b0 += bflo(h5); b1 += bfhi(h5);
        c0 += bflo(h6); c1 += bfhi(h6);
        d0 += bflo(h7); d1 += bfhi(h7);
    }
    for (; p + 3 < p1; p += 4) {
        int s0 = csr[p], s1 = csr[p + 1], s2 = csr[p + 2], s3 = csr[p + 3];
        uint h0 = H2[(size_t)s0 * 64 + lane];
        uint h1 = H2[(size_t)s1 * 64 + lane];
        uint h2 = H2[(size_t)s2 * 64 + lane];
        uint h3 = H2[(size_t)s3 * 64 + lane];
        a0 += bflo(h0); a1 += bfhi(h0);
        b0 += bflo(h1); b1 += bfhi(h1);
        c0 += bflo(h2); c1 += bfhi(h2);
        d0 += bflo(h3); d1 += bfhi(h3);
    }
    for (; p < p1; p++) {
        uint h0 = H2[(size_t)csr[p] * 64 + lane];
        a0 += bflo(h0); a1 += bfhi(h0);
    }
    float2 bb = *(const float2*)(bias + 2 * lane);
    float r0 = fmaf((a0 + b0) + (c0 + d0), di, bb.x);
    float r1 = fmaf((a1 + b1) + (c1 + d1), di, bb.y);
    Y2[(size_t)i * 64 + lane] = (uint)f2bf(r0) | ((uint)f2bf(r1) << 16);

    // fused GraphNorm partial stats
    __shared__ float ls[4][128], lq[4][128];
    ls[wid][2 * lane]     = r0;      ls[wid][2 * lane + 1] = r1;
    lq[wid][2 * lane]     = r0 * r0; lq[wid][2 * lane + 1] = r1 * r1;
    __syncthreads();
    if (threadIdx.x < 128) {
        int f = threadIdx.x;
        float s = (ls[0][f] + ls[1][f]) + (ls[2][f] + ls[3][f]);
        float q = (lq[0][f] + lq[1][f]) + (lq[2][f] + lq[3][f]);
        int sh = (blockIdx.x & 7) * 128 + f;
        atomicAdd(&psumG[sh], s);
        atomicAdd(&psqG[sh], q);
    }
}

// ---------------- GraphNorm params from fused sharded accumulators ----------------
__global__ void k_nparams(const float* __restrict__ psum, const float* __restrict__ psq,
                          const float* __restrict__ w, const float* __restrict__ b,
                          const float* __restrict__ a,
                          float* __restrict__ mul, float* __restrict__ add) {
    int f = threadIdx.x;
    float s = 0.f, q = 0.f;
    #pragma unroll
    for (int j = 0; j < 8; j++) { s += psum[j * 128 + f]; q += psq[j * 128 + f]; }
    const float invn = 1.0f / (float)NN;
    float m = s * invn;
    float ex2 = q * invn;
    float av = a[f];
    float var = ex2 - m * m * (2.f * av - av * av);
    float inv = rsqrtf(var + EPSV);
    mul[f] = w[f] * inv;
    add[f] = b[f] - w[f] * inv * av * m;
}

// ---------------- fused MLP head (MFMA): out = relu(T(X)@W + b0h) @ v1 + b1 ----------------
__global__ __launch_bounds__(256)
void k_mlp(const uint* __restrict__ Xp, const ushort* __restrict__ Wf,
           const float* __restrict__ mul, const float* __restrict__ add,
           const float* __restrict__ b0h, const float* __restrict__ v1,
           const float* __restrict__ b1, float* __restrict__ out) {
    int strip = blockIdx.x * 4 + (threadIdx.x >> 6);
    if (strip >= NSTRIP) return;
    int lane = threadIdx.x & 63;
    int quad = lane >> 4;
    int m = lane & 15;
    int row = strip * 16 + m;

    BF8 a[4];
    #pragma unroll
    for (int kt = 0; kt < 4; kt++) {
        int f = kt * 32 + quad * 8;
        uint4 xu = *(const uint4*)(Xp + (size_t)row * 64 + kt * 16 + quad * 4);
        float4 m0 = *(const float4*)(mul + f);
        float4 m1 = *(const float4*)(mul + f + 4);
        float4 a0 = *(const float4*)(add + f);
        float4 a1 = *(const float4*)(add + f + 4);
        uint xs[4] = {xu.x, xu.y, xu.z, xu.w};
        float mm[8] = {m0.x, m0.y, m0.z, m0.w, m1.x, m1.y, m1.z, m1.w};
        float aa[8] = {a0.x, a0.y, a0.z, a0.w, a1.x, a1.y, a1.z, a1.w};
        #pragma unroll
        for (int p = 0; p < 4; p++) {
            float lo = bflo(xs[p]), hi = bfhi(xs[p]);
            a[kt].us[2 * p]     = f2bf(fmaxf(0.f, fmaf(lo, mm[2 * p],     aa[2 * p])));
            a[kt].us[2 * p + 1] = f2bf(fmaxf(0.f, fmaf(hi, mm[2 * p + 1], aa[2 * p + 1])));
        }
    }

    float part[4] = {0.f, 0.f, 0.f, 0.f};
    #pragma unroll
    for (int nt = 0; nt < 8; nt++) {
        f32x4 acc = {0.f, 0.f, 0.f, 0.f};
        #pragma unroll
        for (int kt = 0; kt < 4; kt++) {
            BF8 b;
            b.u4 = ((const uint4*)Wf)[(nt * 4 + kt) * 64 + lane];
            acc = __builtin_amdgcn_mfma_f32_16x16x32_bf16(a[kt].v, b.v, acc, 0, 0, 0);
        }
        int colg = nt * 16 + m;
        float bb = b0h[colg];
        float vv = v1[colg];
        #pragma unroll
        for (int r = 0; r < 4; r++)
            part[r] = fmaf(fmaxf(0.f, acc[r] + bb), vv, part[r]);
    }
    #pragma unroll
    for (int r = 0; r < 4; r++) {
        #pragma unroll
        for (int off = 1; off < 16; off <<= 1)
            part[r] += __shfl_xor(part[r], off, 64);
    }
    if (m == 0) {
        float ob = b1[0];
        #pragma unroll
        for (int r = 0; r < 4; r++)
            out[strip * 16 + quad * 4 + r] = part[r] + ob;
    }
}

// ---------------- launch ----------------
static inline char* wsalloc(char*& p, size_t bytes) {
    char* r = p;
    p += (bytes + 255) & ~(size_t)255;
    return r;
}

extern "C" void kernel_launch(void* const* d_in, const int* in_sizes, int n_in,
                              void* d_out, int out_size, void* d_ws, size_t ws_size,
                              hipStream_t stream) {
    const float* x     = (const float*)d_in[0];
    const int*   ei    = (const int*)d_in[1];
    const int*   row   = ei;
    const int*   col   = ei + NE;
    const float* W0    = (const float*)d_in[2];
    const float* b0    = (const float*)d_in[3];
    const float* W1    = (const float*)d_in[4];
    const float* b1    = (const float*)d_in[5];
    const float* gn0w  = (const float*)d_in[6];
    const float* gn0b  = (const float*)d_in[7];
    const float* gn0a  = (const float*)d_in[8];
    const float* gn1w  = (const float*)d_in[9];
    const float* gn1b  = (const float*)d_in[10];
    const float* gn1a  = (const float*)d_in[11];
    const float* lin0w = (const float*)d_in[12];
    const float* lin0b = (const float*)d_in[13];
    const float* lin1w = (const float*)d_in[14];
    const float* lin1b = (const float*)d_in[15];
    float* out = (float*)d_out;

    char* p = (char*)d_ws;
    ushort* bufA   = (ushort*)wsalloc(p, (size_t)NN * DD * 2);   // bf16 g = h*dinv
    ushort* bufB   = (ushort*)wsalloc(p, (size_t)NN * DD * 2);   // bf16 agg out
    int*    csr    = (int*)   wsalloc(p, (size_t)NE * 4);        // src only
    uint*   ebuf   = (uint*)  wsalloc(p, (size_t)NE * 4);        // packed (src<<9)|local
    int*    blk_off= (int*)   wsalloc(p, (size_t)NHB * 256 * 4);
    int*    bucket_cnt = (int*)wsalloc(p, 256 * 4);
    int*    bucket_base= (int*)wsalloc(p, 257 * 4);
    int*    row_ptr= (int*)   wsalloc(p, (size_t)(NN + 1) * 4);
    float*  dinv   = (float*) wsalloc(p, (size_t)NN * 4);
    float*  statsG = (float*) wsalloc(p, 4096 * 4);   // 2 stages x (8x128 sum | 8x128 sq)
    float*  mulv   = (float*) wsalloc(p, DD * 4);
    float*  addv   = (float*) wsalloc(p, DD * 4);
    ushort* Wf     = (ushort*)wsalloc(p, 3 * 2048 * 8 * 2);      // 3 prepped weights

    hipMemsetAsync(bucket_cnt, 0, 256 * 4, stream);
    hipMemsetAsync(statsG, 0, 4096 * 4, stream);

    // graph build: bucketed counting sort; degrees/row_ptr/dinv derived bucket-locally
    kb_hist <<<NHB, 256, 0, stream>>>(col, bucket_cnt, blk_off);
    kb_scan <<<1, 256, 0, stream>>>(bucket_cnt, bucket_base);
    kb_place<<<NHB, 256, 0, stream>>>(row, col, bucket_base, blk_off, ebuf);
    kb_fin  <<<NBUCK, 256, 0, stream>>>(ebuf, bucket_base, row_ptr, dinv, csr);

    // weight prep
    k_prepw3<<<24, 256, 0, stream>>>(W0, W1, lin0w, Wf);
    ushort* Wf0 = Wf;
    ushort* Wf1 = Wf + 2048 * 8;
    ushort* Wf2 = Wf + 2 * 2048 * 8;

    const int GB = (NSTRIP + 3) / 4;   // 1563 blocks for gemm-shaped kernels

    // stage 1
    k_gemmA<<<GB, 256, 0, stream>>>(x, Wf0, dinv, bufA);
    k_agg2 <<<NN / 4, 256, 0, stream>>>((const uint*)bufA, row_ptr, csr, dinv, b0,
                                        (uint*)bufB, statsG, statsG + 1024);
    k_nparams<<<1, 128, 0, stream>>>(statsG, statsG + 1024, gn0w, gn0b, gn0a, mulv, addv);

    // stage 2
    k_gemmB<<<GB, 256, 0, stream>>>((const uint*)bufB, Wf1, mulv, addv, dinv, bufA);
    k_agg2 <<<NN / 4, 256, 0, stream>>>((const uint*)bufA, row_ptr, csr, dinv, b1,
                                        (uint*)bufB, statsG + 2048, statsG + 3072);
    k_nparams<<<1, 128, 0, stream>>>(statsG + 2048, statsG + 3072, gn1w, gn1b, gn1a, mulv, addv);

    // fused MLP head
    k_mlp<<<GB, 256, 0, stream>>>((const uint*)bufB, Wf2, mulv, addv,
                                  lin0b, lin1w, lin1b, out);

    (void)in_sizes; (void)n_in; (void)out_size; (void)ws_size;
}

// Round 4
// 407.151 us; speedup vs baseline: 1.2300x; 1.0229x over previous
//
#include <hip/hip_runtime.h>

// ---------------- problem constants ----------------
#define NN 100000      // nodes
#define NE 1600000     // edges (without self loops)
#define DD 128         // feature dim
#define EPSV 1e-5f

#define NSTRIP 6250            // NN/16 row-strips for MFMA gemms

// bucket sort: 196 buckets of 512 nodes; 782 hist/place blocks of 2048 edges
#define BSHIFT 9
#define NBUCK 196
#define EPB 2048
#define NHB 782

// 2-slice feature layout: slice s holds features [64s,64s+64) as 32 uints
// (128 B row = exactly one L2 line -> no fetch inflation on random gathers).
#define SL_U (NN * 32)         // uints per slice
#define SL_US (NN * 64)        // ushorts per slice
#define NSHARD 32              // stats atomic shards

typedef __attribute__((ext_vector_type(8))) __bf16 bf16x8;
typedef __attribute__((ext_vector_type(4))) float f32x4;

union BF8 {                // bit-level construction of MFMA bf16 fragments
    ushort  us[8];
    uint    ui[4];
    uint4   u4;
    bf16x8  v;
};

__device__ __forceinline__ ushort f2bf(float f) {   // RNE fp32 -> bf16 bits
    uint u = __float_as_uint(f);
    return (ushort)((u + 0x7fffu + ((u >> 16) & 1u)) >> 16);
}
__device__ __forceinline__ float bflo(uint u) { return __uint_as_float(u << 16); }
__device__ __forceinline__ float bfhi(uint u) { return __uint_as_float(u & 0xffff0000u); }

// ---------------- bucketed counting sort (write-local CSR build) ----------------
__global__ __launch_bounds__(256)
void kb_hist(const int* __restrict__ col, int* __restrict__ bucket_cnt,
             int* __restrict__ blk_off) {
    __shared__ int h[256];
    int t = threadIdx.x;
    h[t] = 0;
    __syncthreads();
    int e0 = blockIdx.x * EPB;
    #pragma unroll
    for (int j = 0; j < 8; j++) {
        int e = e0 + t + j * 256;
        if (e < NE) atomicAdd(&h[col[e] >> BSHIFT], 1);
    }
    __syncthreads();
    int c = h[t];
    blk_off[blockIdx.x * 256 + t] = c ? atomicAdd(&bucket_cnt[t], c) : 0;
}

__global__ void kb_scan(const int* __restrict__ bucket_cnt, int* __restrict__ bucket_base) {
    __shared__ int s[256];
    int t = threadIdx.x;
    int v = bucket_cnt[t];
    s[t] = v;
    __syncthreads();
    for (int off = 1; off < 256; off <<= 1) {
        int u = (t >= off) ? s[t - off] : 0;
        __syncthreads();
        s[t] += u;
        __syncthreads();
    }
    bucket_base[t] = s[t] - v;
    if (t == 255) bucket_base[256] = s[255];
}

__global__ __launch_bounds__(256)
void kb_place(const int* __restrict__ row, const int* __restrict__ col,
              const int* __restrict__ bucket_base, const int* __restrict__ blk_off,
              uint* __restrict__ ebuf) {
    __shared__ int cur[256];
    int t = threadIdx.x;
    cur[t] = bucket_base[t] + blk_off[blockIdx.x * 256 + t];
    __syncthreads();
    int e0 = blockIdx.x * EPB;
    #pragma unroll
    for (int j = 0; j < 8; j++) {
        int e = e0 + t + j * 256;
        if (e < NE) {
            int c = col[e];
            int pos = atomicAdd(&cur[c >> BSHIFT], 1);
            ebuf[pos] = ((uint)row[e] << BSHIFT) | (uint)(c & ((1 << BSHIFT) - 1));
        }
    }
}

__global__ __launch_bounds__(256)
void kb_fin(const uint* __restrict__ ebuf, const int* __restrict__ bucket_base,
            int* __restrict__ row_ptr, float* __restrict__ dinv,
            int* __restrict__ csr) {
    __shared__ int deg[512];
    __shared__ int scn[256];
    int b = blockIdx.x;
    int n0 = b << BSHIFT;
    int t = threadIdx.x;
    deg[t] = 0; deg[t + 256] = 0;
    __syncthreads();
    int s = bucket_base[b], e = bucket_base[b + 1];
    for (int p = s + t; p < e; p += 256)
        atomicAdd(&deg[ebuf[p] & 511u], 1);
    __syncthreads();
    int d0 = deg[2 * t], d1 = deg[2 * t + 1];
    int pairsum = d0 + d1;
    scn[t] = pairsum;
    __syncthreads();
    for (int off = 1; off < 256; off <<= 1) {
        int u = (t >= off) ? scn[t - off] : 0;
        __syncthreads();
        scn[t] += u;
        __syncthreads();
    }
    int base = s + scn[t] - pairsum;          // global CSR offset of node n0+2t
    int node0 = n0 + 2 * t;
    if (node0 < NN)     { row_ptr[node0]     = base;      dinv[node0]     = rsqrtf((float)(d0 + 1)); }
    if (node0 + 1 < NN) { row_ptr[node0 + 1] = base + d0; dinv[node0 + 1] = rsqrtf((float)(d1 + 1)); }
    __syncthreads();                           // before reusing deg[] as cursors
    deg[2 * t] = base;
    deg[2 * t + 1] = base + d0;
    __syncthreads();
    for (int p = s + t; p < e; p += 256) {
        uint r = ebuf[p];
        int pos = atomicAdd(&deg[r & 511u], 1);
        csr[pos] = (int)(r >> BSHIFT);         // 4B record: src only
    }
    if (b == 0 && t == 0) row_ptr[NN] = NE;
}

// ---------------- weight prep: 3x W[128x128] fp32 -> B-fragment order bf16 ----------------
__global__ void k_prepw3(const float* __restrict__ WA, const float* __restrict__ WB,
                         const float* __restrict__ WC, ushort* __restrict__ Wf) {
    int which = blockIdx.x >> 3;
    const float* W = (which == 0) ? WA : ((which == 1) ? WB : WC);
    int t = (blockIdx.x & 7) * 256 + threadIdx.x;    // 0..2047
    int lane = t & 63;
    int kt = (t >> 6) & 3;
    int nt = t >> 8;
    int quad = lane >> 4;
    int n = nt * 16 + (lane & 15);
    BF8 f;
    #pragma unroll
    for (int j = 0; j < 8; j++)
        f.us[j] = f2bf(W[(kt * 32 + quad * 8 + j) * DD + n]);
    ((uint4*)(Wf + (size_t)which * 2048 * 8))[t] = f.u4;
}

// ---------------- GEMM1: G_bf16[2-slice] = (bf16(X_f32) @ Wf) * dinv[row] ----------------
__global__ __launch_bounds__(256)
void k_gemmA(const float* __restrict__ X, const ushort* __restrict__ Wf,
             const float* __restrict__ dinv, ushort* __restrict__ Y) {
    int strip = blockIdx.x * 4 + (threadIdx.x >> 6);
    if (strip >= NSTRIP) return;
    int lane = threadIdx.x & 63;
    int quad = lane >> 4;
    int m = lane & 15;
    int row = strip * 16 + m;

    BF8 a[4];
    #pragma unroll
    for (int kt = 0; kt < 4; kt++) {
        const float* xp = X + (size_t)row * DD + kt * 32 + quad * 8;
        float4 v0 = *(const float4*)xp;
        float4 v1 = *(const float4*)(xp + 4);
        a[kt].us[0] = f2bf(v0.x); a[kt].us[1] = f2bf(v0.y);
        a[kt].us[2] = f2bf(v0.z); a[kt].us[3] = f2bf(v0.w);
        a[kt].us[4] = f2bf(v1.x); a[kt].us[5] = f2bf(v1.y);
        a[kt].us[6] = f2bf(v1.z); a[kt].us[7] = f2bf(v1.w);
    }

    float4 dv = *(const float4*)(dinv + strip * 16 + quad * 4);
    float dvr[4] = {dv.x, dv.y, dv.z, dv.w};

    #pragma unroll
    for (int nt = 0; nt < 8; nt++) {
        f32x4 acc = {0.f, 0.f, 0.f, 0.f};
        #pragma unroll
        for (int kt = 0; kt < 4; kt++) {
            BF8 b;
            b.u4 = ((const uint4*)Wf)[(nt * 4 + kt) * 64 + lane];
            acc = __builtin_amdgcn_mfma_f32_16x16x32_bf16(a[kt].v, b.v, acc, 0, 0, 0);
        }
        // sliced write: slice = nt>>2, local ushort col = (nt&3)*16 + m
        ushort* yb = Y + (size_t)(nt >> 2) * SL_US + (nt & 3) * 16 + m;
        #pragma unroll
        for (int r = 0; r < 4; r++)
            yb[(size_t)(strip * 16 + quad * 4 + r) * 64] = f2bf(acc[r] * dvr[r]);
    }
}

// -------- GEMM2: G = (bf16(relu(norm(X_2slice))) @ Wf) * dinv ; norm params from partials ----
__global__ __launch_bounds__(256)
void k_gemmB(const uint* __restrict__ Xp, const ushort* __restrict__ Wf,
             const float* __restrict__ psum, const float* __restrict__ psq,
             const float* __restrict__ gw, const float* __restrict__ gb,
             const float* __restrict__ ga,
             const float* __restrict__ dinv, ushort* __restrict__ Y) {
    __shared__ float smul[128], sadd[128];
    {
        int f = threadIdx.x;
        if (f < 128) {
            float s = 0.f, q = 0.f;
            #pragma unroll
            for (int sh = 0; sh < NSHARD; sh++) { s += psum[sh * 128 + f]; q += psq[sh * 128 + f]; }
            const float invn = 1.0f / (float)NN;
            float mm = s * invn, ex2 = q * invn, av = ga[f];
            float var = ex2 - mm * mm * (2.f * av - av * av);
            float inv = rsqrtf(var + EPSV);
            smul[f] = gw[f] * inv;
            sadd[f] = gb[f] - gw[f] * inv * av * mm;
        }
    }
    __syncthreads();
    int strip = blockIdx.x * 4 + (threadIdx.x >> 6);
    if (strip >= NSTRIP) return;
    int lane = threadIdx.x & 63;
    int quad = lane >> 4;
    int m = lane & 15;
    int row = strip * 16 + m;

    BF8 a[4];
    #pragma unroll
    for (int kt = 0; kt < 4; kt++) {
        int f = kt * 32 + quad * 8;
        // sliced read: slice = kt>>1, local uint idx = (kt&1)*16 + quad*4
        uint4 xu = *(const uint4*)(Xp + (size_t)(kt >> 1) * SL_U + (size_t)row * 32
                                   + (kt & 1) * 16 + quad * 4);
        float4 m0 = *(const float4*)(smul + f);
        float4 m1 = *(const float4*)(smul + f + 4);
        float4 a0 = *(const float4*)(sadd + f);
        float4 a1 = *(const float4*)(sadd + f + 4);
        uint xs[4] = {xu.x, xu.y, xu.z, xu.w};
        float mm[8] = {m0.x, m0.y, m0.z, m0.w, m1.x, m1.y, m1.z, m1.w};
        float aa[8] = {a0.x, a0.y, a0.z, a0.w, a1.x, a1.y, a1.z, a1.w};
        #pragma unroll
        for (int p = 0; p < 4; p++) {
            float lo = bflo(xs[p]), hi = bfhi(xs[p]);
            a[kt].us[2 * p]     = f2bf(fmaxf(0.f, fmaf(lo, mm[2 * p],     aa[2 * p])));
            a[kt].us[2 * p + 1] = f2bf(fmaxf(0.f, fmaf(hi, mm[2 * p + 1], aa[2 * p + 1])));
        }
    }

    float4 dv = *(const float4*)(dinv + strip * 16 + quad * 4);
    float dvr[4] = {dv.x, dv.y, dv.z, dv.w};

    #pragma unroll
    for (int nt = 0; nt < 8; nt++) {
        f32x4 acc = {0.f, 0.f, 0.f, 0.f};
        #pragma unroll
        for (int kt = 0; kt < 4; kt++) {
            BF8 b;
            b.u4 = ((const uint4*)Wf)[(nt * 4 + kt) * 64 + lane];
            acc = __builtin_amdgcn_mfma_f32_16x16x32_bf16(a[kt].v, b.v, acc, 0, 0, 0);
        }
        ushort* yb = Y + (size_t)(nt >> 2) * SL_US + (nt & 3) * 16 + m;
        #pragma unroll
        for (int r = 0; r < 4; r++)
            yb[(size_t)(strip * 16 + quad * 4 + r) * 64] = f2bf(acc[r] * dvr[r]);
    }
}

// ---------------- 2-slice aggregation + fused GraphNorm stats ----------------
// bid = grp*8 + slice*4 + sub: round-robin dispatch puts slice 0 on XCDs 0-3,
// slice 1 on XCDs 4-7 -> per-XCD gather working set 12.8 MB (vs 25.6), and
// each H line is touched ~4x per XCD (vs ~2x) -> higher L2 hit.
// Wave = 1 node, 32 active lanes (128 B row = 1 L2 line); 16 gathers in
// flight to keep per-CU outstanding-line count at round-0 levels.
__global__ __launch_bounds__(256)
void k_agg2s(const uint* __restrict__ H, const int* __restrict__ row_ptr,
             const int* __restrict__ csr, const float* __restrict__ dinv,
             const float* __restrict__ bias, uint* __restrict__ Y,
             float* __restrict__ psumG, float* __restrict__ psqG) {
    const int lane = threadIdx.x & 63;
    const int wid  = threadIdx.x >> 6;
    const int bid  = blockIdx.x;
    const int slice = (bid >> 2) & 1;
    const int ng = (bid >> 3) * 4 + (bid & 3);      // node-group 0..24999
    const int i = __builtin_amdgcn_readfirstlane(ng * 4 + wid);
    const int p0 = row_ptr[i], p1 = row_ptr[i + 1];
    const float di = dinv[i];
    const uint* __restrict__ Hs = H + (size_t)slice * SL_U;
    uint* __restrict__ Ys = Y + (size_t)slice * SL_U;

    float r0 = 0.f, r1 = 0.f;
    if (lane < 32) {
        uint su = Hs[(size_t)i * 32 + lane];
        float a0 = bflo(su), a1 = bfhi(su);        // self loop term g[i]
        float b0 = 0.f, b1 = 0.f, c0 = 0.f, c1 = 0.f, d0 = 0.f, d1 = 0.f;
        int p = p0;
        for (; p + 15 < p1; p += 16) {             // 16 loads in flight
            int s0 = csr[p],      s1 = csr[p + 1],  s2 = csr[p + 2],  s3 = csr[p + 3];
            int s4 = csr[p + 4],  s5 = csr[p + 5],  s6 = csr[p + 6],  s7 = csr[p + 7];
            int s8 = csr[p + 8],  s9 = csr[p + 9],  sa = csr[p + 10], sb = csr[p + 11];
            int sc = csr[p + 12], sd = csr[p + 13], se = csr[p + 14], sf = csr[p + 15];
            uint h0 = Hs[(size_t)s0 * 32 + lane];
            uint h1 = Hs[(size_t)s1 * 32 + lane];
            uint h2 = Hs[(size_t)s2 * 32 + lane];
            uint h3 = Hs[(size_t)s3 * 32 + lane];
            uint h4 = Hs[(size_t)s4 * 32 + lane];
            uint h5 = Hs[(size_t)s5 * 32 + lane];
            uint h6 = Hs[(size_t)s6 * 32 + lane];
            uint h7 = Hs[(size_t)s7 * 32 + lane];
            uint h8 = Hs[(size_t)s8 * 32 + lane];
            uint h9 = Hs[(size_t)s9 * 32 + lane];
            uint ha = Hs[(size_t)sa * 32 + lane];
            uint hb = Hs[(size_t)sb * 32 + lane];
            uint hc = Hs[(size_t)sc * 32 + lane];
            uint hd = Hs[(size_t)sd * 32 + lane];
            uint he = Hs[(size_t)se * 32 + lane];
            uint hf = Hs[(size_t)sf * 32 + lane];
            a0 += bflo(h0); a1 += bfhi(h0);
            b0 += bflo(h1); b1 += bfhi(h1);
            c0 += bflo(h2); c1 += bfhi(h2);
            d0 += bflo(h3); d1 += bfhi(h3);
            a0 += bflo(h4); a1 += bfhi(h4);
            b0 += bflo(h5); b1 += bfhi(h5);
            c0 += bflo(h6); c1 += bfhi(h6);
            d0 += bflo(h7); d1 += bfhi(h7);
            a0 += bflo(h8); a1 += bfhi(h8);
            b0 += bflo(h9); b1 += bfhi(h9);
            c0 += bflo(ha); c1 += bfhi(ha);
            d0 += bflo(hb); d1 += bfhi(hb);
            a0 += bflo(hc); a1 += bfhi(hc);
            b0 += bflo(hd); b1 += bfhi(hd);
            c0 += bflo(he); c1 += bfhi(he);
            d0 += bflo(hf); d1 += bfhi(hf);
        }
        for (; p + 3 < p1; p += 4) {
            int s0 = csr[p], s1 = csr[p + 1], s2 = csr[p + 2], s3 = csr[p + 3];
            uint h0 = Hs[(size_t)s0 * 32 + lane];
            uint h1 = Hs[(size_t)s1 * 32 + lane];
            uint h2 = Hs[(size_t)s2 * 32 + lane];
            uint h3 = Hs[(size_t)s3 * 32 + lane];
            a0 += bflo(h0); a1 += bfhi(h0);
            b0 += bflo(h1); b1 += bfhi(h1);
            c0 += bflo(h2); c1 += bfhi(h2);
            d0 += bflo(h3); d1 += bfhi(h3);
        }
        for (; p < p1; p++) {
            uint h0 = Hs[(size_t)csr[p] * 32 + lane];
            a0 += bflo(h0); a1 += bfhi(h0);
        }
        float2 bb = *(const float2*)(bias + slice * 64 + 2 * lane);
        r0 = fmaf((a0 + b0) + (c0 + d0), di, bb.x);
        r1 = fmaf((a1 + b1) + (c1 + d1), di, bb.y);
        Ys[(size_t)i * 32 + lane] = (uint)f2bf(r0) | ((uint)f2bf(r1) << 16);
    }

    // fused GraphNorm partial stats (32-way sharded atomics: ~781 adds/address)
    __shared__ float ls[4][64], lq[4][64];
    if (lane < 32) {
        ls[wid][2 * lane]     = r0;      ls[wid][2 * lane + 1] = r1;
        lq[wid][2 * lane]     = r0 * r0; lq[wid][2 * lane + 1] = r1 * r1;
    }
    __syncthreads();
    if (threadIdx.x < 64) {
        int t = threadIdx.x;
        float s = (ls[0][t] + ls[1][t]) + (ls[2][t] + ls[3][t]);
        float q = (lq[0][t] + lq[1][t]) + (lq[2][t] + lq[3][t]);
        int sh = (bid >> 3) & (NSHARD - 1);
        atomicAdd(&psumG[sh * 128 + slice * 64 + t], s);
        atomicAdd(&psqG [sh * 128 + slice * 64 + t], q);
    }
}

// ------- fused MLP head (MFMA): out = relu(T(norm(X))@W + b0h) @ v1 + b1 ; norm folded ------
__global__ __launch_bounds__(256)
void k_mlp(const uint* __restrict__ Xp, const ushort* __restrict__ Wf,
           const float* __restrict__ psum, const float* __restrict__ psq,
           const float* __restrict__ gw, const float* __restrict__ gb,
           const float* __restrict__ ga,
           const float* __restrict__ b0h, const float* __restrict__ v1,
           const float* __restrict__ b1, float* __restrict__ out) {
    __shared__ float smul[128], sadd[128];
    {
        int f = threadIdx.x;
        if (f < 128) {
            float s = 0.f, q = 0.f;
            #pragma unroll
            for (int sh = 0; sh < NSHARD; sh++) { s += psum[sh * 128 + f]; q += psq[sh * 128 + f]; }
            const float invn = 1.0f / (float)NN;
            float mm = s * invn, ex2 = q * invn, av = ga[f];
            float var = ex2 - mm * mm * (2.f * av - av * av);
            float inv = rsqrtf(var + EPSV);
            smul[f] = gw[f] * inv;
            sadd[f] = gb[f] - gw[f] * inv * av * mm;
        }
    }
    __syncthreads();
    int strip = blockIdx.x * 4 + (threadIdx.x >> 6);
    if (strip >= NSTRIP) return;
    int lane = threadIdx.x & 63;
    int quad = lane >> 4;
    int m = lane & 15;
    int row = strip * 16 + m;

    BF8 a[4];
    #pragma unroll
    for (int kt = 0; kt < 4; kt++) {
        int f = kt * 32 + quad * 8;
        uint4 xu = *(const uint4*)(Xp + (size_t)(kt >> 1) * SL_U + (size_t)row * 32
                                   + (kt & 1) * 16 + quad * 4);
        float4 m0 = *(const float4*)(smul + f);
        float4 m1 = *(const float4*)(smul + f + 4);
        float4 a0 = *(const float4*)(sadd + f);
        float4 a1 = *(const float4*)(sadd + f + 4);
        uint xs[4] = {xu.x, xu.y, xu.z, xu.w};
        float mm[8] = {m0.x, m0.y, m0.z, m0.w, m1.x, m1.y, m1.z, m1.w};
        float aa[8] = {a0.x, a0.y, a0.z, a0.w, a1.x, a1.y, a1.z, a1.w};
        #pragma unroll
        for (int p = 0; p < 4; p++) {
            float lo = bflo(xs[p]), hi = bfhi(xs[p]);
            a[kt].us[2 * p]     = f2bf(fmaxf(0.f, fmaf(lo, mm[2 * p],     aa[2 * p])));
            a[kt].us[2 * p + 1] = f2bf(fmaxf(0.f, fmaf(hi, mm[2 * p + 1], aa[2 * p + 1])));
        }
    }

    float part[4] = {0.f, 0.f, 0.f, 0.f};
    #pragma unroll
    for (int nt = 0; nt < 8; nt++) {
        f32x4 acc = {0.f, 0.f, 0.f, 0.f};
        #pragma unroll
        for (int kt = 0; kt < 4; kt++) {
            BF8 b;
            b.u4 = ((const uint4*)Wf)[(nt * 4 + kt) * 64 + lane];
            acc = __builtin_amdgcn_mfma_f32_16x16x32_bf16(a[kt].v, b.v, acc, 0, 0, 0);
        }
        int colg = nt * 16 + m;
        float bb = b0h[colg];
        float vv = v1[colg];
        #pragma unroll
        for (int r = 0; r < 4; r++)
            part[r] = fmaf(fmaxf(0.f, acc[r] + bb), vv, part[r]);
    }
    #pragma unroll
    for (int r = 0; r < 4; r++) {
        #pragma unroll
        for (int off = 1; off < 16; off <<= 1)
            part[r] += __shfl_xor(part[r], off, 64);
    }
    if (m == 0) {
        float ob = b1[0];
        #pragma unroll
        for (int r = 0; r < 4; r++)
            out[strip * 16 + quad * 4 + r] = part[r] + ob;
    }
}

// ---------------- launch ----------------
static inline char* wsalloc(char*& p, size_t bytes) {
    char* r = p;
    p += (bytes + 255) & ~(size_t)255;
    return r;
}

extern "C" void kernel_launch(void* const* d_in, const int* in_sizes, int n_in,
                              void* d_out, int out_size, void* d_ws, size_t ws_size,
                              hipStream_t stream) {
    const float* x     = (const float*)d_in[0];
    const int*   ei    = (const int*)d_in[1];
    const int*   row   = ei;
    const int*   col   = ei + NE;
    const float* W0    = (const float*)d_in[2];
    const float* b0    = (const float*)d_in[3];
    const float* W1    = (const float*)d_in[4];
    const float* b1    = (const float*)d_in[5];
    const float* gn0w  = (const float*)d_in[6];
    const float* gn0b  = (const float*)d_in[7];
    const float* gn0a  = (const float*)d_in[8];
    const float* gn1w  = (const float*)d_in[9];
    const float* gn1b  = (const float*)d_in[10];
    const float* gn1a  = (const float*)d_in[11];
    const float* lin0w = (const float*)d_in[12];
    const float* lin0b = (const float*)d_in[13];
    const float* lin1w = (const float*)d_in[14];
    const float* lin1b = (const float*)d_in[15];
    float* out = (float*)d_out;

    char* p = (char*)d_ws;
    ushort* bufA   = (ushort*)wsalloc(p, (size_t)NN * DD * 2);   // bf16 g, 2-slice
    ushort* bufB   = (ushort*)wsalloc(p, (size_t)NN * DD * 2);   // bf16 agg out, 2-slice
    int*    csr    = (int*)   wsalloc(p, (size_t)NE * 4);        // src only
    uint*   ebuf   = (uint*)  wsalloc(p, (size_t)NE * 4);        // packed (src<<9)|local
    int*    blk_off= (int*)   wsalloc(p, (size_t)NHB * 256 * 4);
    int*    bucket_cnt = (int*)wsalloc(p, 256 * 4);
    int*    bucket_base= (int*)wsalloc(p, 257 * 4);
    int*    row_ptr= (int*)   wsalloc(p, (size_t)(NN + 1) * 4);
    float*  dinv   = (float*) wsalloc(p, (size_t)NN * 4);
    float*  statsG = (float*) wsalloc(p, 4 * NSHARD * 128 * 4);  // 2 stages x (sum|sq)[32][128]
    ushort* Wf     = (ushort*)wsalloc(p, 3 * 2048 * 8 * 2);      // 3 prepped weights

    hipMemsetAsync(bucket_cnt, 0, 256 * 4, stream);
    hipMemsetAsync(statsG, 0, 4 * NSHARD * 128 * 4, stream);

    // graph build: bucketed counting sort; degrees/row_ptr/dinv derived bucket-locally
    kb_hist <<<NHB, 256, 0, stream>>>(col, bucket_cnt, blk_off);
    kb_scan <<<1, 256, 0, stream>>>(bucket_cnt, bucket_base);
    kb_place<<<NHB, 256, 0, stream>>>(row, col, bucket_base, blk_off, ebuf);
    kb_fin  <<<NBUCK, 256, 0, stream>>>(ebuf, bucket_base, row_ptr, dinv, csr);

    // weight prep
    k_prepw3<<<24, 256, 0, stream>>>(W0, W1, lin0w, Wf);
    ushort* Wf0 = Wf;
    ushort* Wf1 = Wf + 2048 * 8;
    ushort* Wf2 = Wf + 2 * 2048 * 8;

    const int GB  = (NSTRIP + 3) / 4;   // 1563 blocks for gemm-shaped kernels
    const int AGB = (NN / 4 / 4) * 8;   // 6250 grps x 8 = 50000 agg blocks

    float* ps0 = statsG;
    float* pq0 = statsG + NSHARD * 128;
    float* ps1 = statsG + 2 * NSHARD * 128;
    float* pq1 = statsG + 3 * NSHARD * 128;

    // stage 1
    k_gemmA<<<GB, 256, 0, stream>>>(x, Wf0, dinv, bufA);
    k_agg2s<<<AGB, 256, 0, stream>>>((const uint*)bufA, row_ptr, csr, dinv, b0,
                                     (uint*)bufB, ps0, pq0);

    // stage 2 (GraphNorm params folded into gemmB prologue)
    k_gemmB<<<GB, 256, 0, stream>>>((const uint*)bufB, Wf1, ps0, pq0,
                                    gn0w, gn0b, gn0a, dinv, bufA);
    k_agg2s<<<AGB, 256, 0, stream>>>((const uint*)bufA, row_ptr, csr, dinv, b1,
                                     (uint*)bufB, ps1, pq1);

    // fused MLP head (GraphNorm params folded into prologue)
    k_mlp<<<GB, 256, 0, stream>>>((const uint*)bufB, Wf2, ps1, pq1,
                                  gn1w, gn1b, gn1a,
                                  lin0b, lin1w, lin1b, out);

    (void)in_sizes; (void)n_in; (void)out_size; (void)ws_size;
}